// Round 3
// baseline (401.894 us; speedup 1.0000x reference)
//
#include <hip/hip_runtime.h>

#define MT 16384   // B*T = 8*2048
#define NT 2048    // OUT
#define KT 2048    // IN
#define BM 256
#define BN 256
#define BK 64
#define NKT (KT / BK)    // 32 K-tiles
#define THREADS 512

typedef __attribute__((ext_vector_type(8))) short short8;     // 8 bf16 (4 VGPRs) MFMA A/B frag
typedef __attribute__((ext_vector_type(16))) float f32x16;    // 32x32 MFMA C/D frag
typedef __attribute__((ext_vector_type(4))) float f32x4;
typedef __attribute__((ext_vector_type(8))) unsigned short ushort8;
typedef __attribute__((ext_vector_type(4))) unsigned short ushort4v;

__device__ __forceinline__ unsigned short f32_bf16(float f) {
    union { float f; unsigned u; } v; v.f = f;
    return (unsigned short)((v.u + 0x7FFFu + ((v.u >> 16) & 1u)) >> 16);
}

// ---- merged preconvert: x (fp32->bf16) then w (int32->bf16), one dispatch ----

__global__ __launch_bounds__(256) void cvt_kernel(const float* __restrict__ x,
                                                  const int* __restrict__ w,
                                                  unsigned short* __restrict__ xb,
                                                  unsigned short* __restrict__ wb) {
    const int b = blockIdx.x;
    if (b < MT * KT / 2048) {
        size_t i = ((size_t)b * 256 + threadIdx.x) * 8;
        float4 v0 = *(const float4*)(x + i);
        float4 v1 = *(const float4*)(x + i + 4);
        ushort8 o;
        o[0] = f32_bf16(v0.x); o[1] = f32_bf16(v0.y); o[2] = f32_bf16(v0.z); o[3] = f32_bf16(v0.w);
        o[4] = f32_bf16(v1.x); o[5] = f32_bf16(v1.y); o[6] = f32_bf16(v1.z); o[7] = f32_bf16(v1.w);
        *(ushort8*)(xb + i) = o;
    } else {
        size_t i = ((size_t)(b - MT * KT / 2048) * 256 + threadIdx.x) * 8;
        int4 v0 = *(const int4*)(w + i);
        int4 v1 = *(const int4*)(w + i + 4);
        ushort8 o;
        o[0] = f32_bf16((float)v0.x); o[1] = f32_bf16((float)v0.y);
        o[2] = f32_bf16((float)v0.z); o[3] = f32_bf16((float)v0.w);
        o[4] = f32_bf16((float)v1.x); o[5] = f32_bf16((float)v1.y);
        o[6] = f32_bf16((float)v1.z); o[7] = f32_bf16((float)v1.w);
        *(ushort8*)(wb + i) = o;
    }
}

// ---- R9: R8 (8-phase, 32x32x16) with CONFLICT-FIXED swizzle ----
//
// R8 post-mortem: slot=(c+row)&7 depends on l31 only at unit rate for the
// 32x32 read pattern (row=l31, c=kh*2+hi) -> lanes with l31 differing by 8
// share a slot (same 4-bank group, different rows) => ~4-way conflict,
// SQ_LDS_BANK_CONFLICT=1.26e7. Fix: slot = (c + row + 2*(row>>3)) & 7 --
// injects the coarse row bits so slots are distinct within consecutive-8,
// stride-8, and stride-16 lane groups. Still bijective per row -> staging
// inverse is cg = (slot - row - 2*(row>>3)) & 7 on the pre-swizzled global
// source; global_load_lds dest stays linear (m104/m173).
//
// Everything else identical to R8/R7 (verified): 8 waves (2M x 4N), per-wave
// 128x64 = 4 M-blocks(32) x 2 N-blocks(32); M interleaved (wave wm owns
// 32-row blocks {2f+wm}); phases 1-2 read A half 0, 3-4 half 1, B read whole
// at phase 1 -> stage rotation:
//   ph1: A(t+1)h1 | ph2: B(t+2)h0 | ph3: A(t+2)h0 | ph4: B(t+2)h1 [vmcnt 6]
//   ph5: A(t+2)h1 | ph6: B(t+3)h0 | ph7: A(t+3)h0 | ph8: B(t+3)h1 [vmcnt 6]
// A/B input layout: elem j = tile[row=base+(lane&31)][k=kh*16+(lane>>5)*8+j].
// C/D layout [m74/m101 + R8-passed]: col=lane&31, row=(reg&3)+8*(reg>>2)+4*(lane>>5).

__device__ __forceinline__ int swz8(int row, int c) {   // logical chunk -> slot
    return (c + row + 2 * (row >> 3)) & 7;
}

__global__ __launch_bounds__(THREADS, 2) void gemm_8ph(
    const unsigned short* __restrict__ Abf, const unsigned short* __restrict__ Bbf,
    const int* __restrict__ sexp, const float* __restrict__ bias,
    float* __restrict__ C)
{
    __shared__ unsigned short As[2 * 2048 * 8];   // 64 KB: [buf][256 rows][8 slots][8 bf16]
    __shared__ unsigned short Bs[2 * 2048 * 8];   // 64 KB

    const int tid  = threadIdx.x;
    const int bn   = blockIdx.x;            // N block; bn == XCD id (8 exact): B-slab L2-resident
    const int bm   = blockIdx.y;
    const int brow0 = bm * BM;
    const int bcol0 = bn * BN;
    const int lane = tid & 63;
    const int wave = tid >> 6;
    const int wm = wave >> 2;               // 0..1  (M, interleaved 32-row blocks 2f+wm)
    const int wn = wave & 3;                // 0..3  (N, contiguous 64-col stripe)
    const int l31 = lane & 31;
    const int hi  = lane >> 5;

    // staging source offsets (ushort units) per (half, ii): slot s = h*1024+ii*512+tid
    // holds logical chunk ((s&7) - row - 2*(row>>3)) & 7 of row s>>3 (inverse swizzle).
    size_t aoff[2][2], boff[2][2];
    #pragma unroll
    for (int h = 0; h < 2; ++h)
        #pragma unroll
        for (int ii = 0; ii < 2; ++ii) {
            const int s   = h * 1024 + ii * 512 + tid;
            const int row = s >> 3;
            const int cg  = ((s & 7) - row - 2 * (row >> 3)) & 7;
            aoff[h][ii] = (size_t)(brow0 + row) * KT + cg * 8;
            boff[h][ii] = (size_t)(bcol0 + row) * KT + cg * 8;
        }

#define GLDS(srcp, dstp)                                                            \
    __builtin_amdgcn_global_load_lds(                                               \
        (const __attribute__((address_space(1))) unsigned int*)(srcp),              \
        (__attribute__((address_space(3))) unsigned int*)(dstp), 16, 0, 0)

    auto stageA = [&](int tile, int h) {
        const int buf = tile & 1;
        const size_t k = (size_t)tile * BK;
        GLDS(Abf + aoff[h][0] + k, As + buf * 16384 + (h * 1024 + wave * 64) * 8);
        GLDS(Abf + aoff[h][1] + k, As + buf * 16384 + (h * 1024 + 512 + wave * 64) * 8);
    };
    auto stageB = [&](int tile, int h) {
        const int buf = tile & 1;
        const size_t k = (size_t)tile * BK;
        GLDS(Bbf + boff[h][0] + k, Bs + buf * 16384 + (h * 1024 + wave * 64) * 8);
        GLDS(Bbf + boff[h][1] + k, Bs + buf * 16384 + (h * 1024 + 512 + wave * 64) * 8);
    };

    f32x16 acc[4][2] = {};
    short8 a[4];      // current phase's A-frags, one per kh (K=16 slice)
    short8 b[2][4];   // whole K-tile's B frags [j][kh] (read at phase 1, held 4 phases)

    auto ldA = [&](int buf, int p) {
        const unsigned short* base = As + buf * 16384;
        const int row = (2 * p + wm) * 32 + l31;
        #pragma unroll
        for (int kh = 0; kh < 4; ++kh)
            a[kh] = *(const short8*)(base + row * 64 + swz8(row, kh * 2 + hi) * 8);
    };
    auto ldB = [&](int buf) {
        const unsigned short* base = Bs + buf * 16384;
        #pragma unroll
        for (int j = 0; j < 2; ++j) {
            const int row = (wn * 2 + j) * 32 + l31;
            #pragma unroll
            for (int kh = 0; kh < 4; ++kh)
                b[j][kh] = *(const short8*)(base + row * 64 + swz8(row, kh * 2 + hi) * 8);
        }
    };
    auto mma = [&](int p) {
        #pragma unroll
        for (int kh = 0; kh < 4; ++kh)
            #pragma unroll
            for (int j = 0; j < 2; ++j)
                acc[p][j] = __builtin_amdgcn_mfma_f32_32x32x16_bf16(
                    a[kh], b[j][kh], acc[p][j], 0, 0, 0);
    };

#define PHASE(buf, p, STAGE_STMT, WAIT_STMT) do {          \
        ldA(buf, p);                                       \
        if ((p) == 0) ldB(buf);                            \
        STAGE_STMT;                                        \
        __builtin_amdgcn_s_barrier();                      \
        asm volatile("s_waitcnt lgkmcnt(0)");              \
        __builtin_amdgcn_sched_barrier(0);                 \
        __builtin_amdgcn_s_setprio(1);                     \
        mma(p);                                            \
        __builtin_amdgcn_s_setprio(0);                     \
        WAIT_STMT;                                         \
        __builtin_amdgcn_s_barrier();                      \
    } while (0)

    // prologue: tile0 fully + 3/4 of tile1; vmcnt(6) leaves tile1's 3 halves in
    // flight, guarantees tile0 landed; barrier publishes across waves.
    stageB(0, 0); stageB(0, 1); stageA(0, 0); stageA(0, 1);
    asm volatile("s_waitcnt vmcnt(4)" ::: "memory");
    stageB(1, 0); stageA(1, 0); stageB(1, 1);
    asm volatile("s_waitcnt vmcnt(6)" ::: "memory");
    __builtin_amdgcn_s_barrier();

    #pragma unroll 1
    for (int i = 0; i < NKT / 2 - 1; ++i) {        // 15 iterations: tiles 0..29
        const int t1 = 2 * i + 1, t2 = 2 * i + 2, t3 = 2 * i + 3;
        PHASE(0, 0, stageA(t1, 1), (void)0);
        PHASE(0, 1, stageB(t2, 0), (void)0);
        PHASE(0, 2, stageA(t2, 0), (void)0);
        PHASE(0, 3, stageB(t2, 1), asm volatile("s_waitcnt vmcnt(6)" ::: "memory"));
        PHASE(1, 0, stageA(t2, 1), (void)0);
        PHASE(1, 1, stageB(t3, 0), (void)0);
        PHASE(1, 2, stageA(t3, 0), (void)0);
        PHASE(1, 3, stageB(t3, 1), asm volatile("s_waitcnt vmcnt(6)" ::: "memory"));
    }

    // epilogue iteration: tiles 30 (buf0), 31 (buf1); drain 4 -> 2 -> 0
    PHASE(0, 0, stageA(NKT - 1, 1), (void)0);
    PHASE(0, 1, (void)0, asm volatile("s_waitcnt vmcnt(4)" ::: "memory"));
    PHASE(0, 2, (void)0, asm volatile("s_waitcnt vmcnt(2)" ::: "memory"));
    PHASE(0, 3, (void)0, asm volatile("s_waitcnt vmcnt(0)" ::: "memory"));
    PHASE(1, 0, (void)0, (void)0);
    PHASE(1, 1, (void)0, (void)0);
    PHASE(1, 2, (void)0, (void)0);
    PHASE(1, 3, (void)0, (void)0);

#undef PHASE
#undef GLDS

    // epilogue: 32x32 C/D layout col = lane&31, row = (reg&3)+8*(reg>>2)+4*(lane>>5)
    // [m74/m101-verified + R8 harness-passed]; f-th M-frag at 32-row block (2f + wm).
    #pragma unroll
    for (int j = 0; j < 2; ++j) {
        const int n  = bcol0 + (wn * 2 + j) * 32 + l31;
        const float sc = ldexpf(1.0f, sexp[n]);   // exact power-of-two scale
        const float bs = bias[n];
        #pragma unroll
        for (int f = 0; f < 4; ++f) {
            const int mbase = brow0 + (2 * f + wm) * 32 + hi * 4;
            #pragma unroll
            for (int reg = 0; reg < 16; ++reg) {
                const int m = mbase + (reg & 3) + 8 * (reg >> 2);
                C[(size_t)m * NT + n] = acc[f][j][reg] * sc + bs;
            }
        }
    }
}

// ---- fallback (no workspace): old verified fused 128x128 kernel ----

__device__ __forceinline__ int swzf(int row, int c) { return row * 8 + ((c + row) & 7); }

__global__ __launch_bounds__(256) void gemm_fb(
    const float* __restrict__ Af32, const int* __restrict__ Wi32,
    const int* __restrict__ sexp, const float* __restrict__ bias,
    float* __restrict__ C)
{
    __shared__ unsigned short As[128 * 64];
    __shared__ unsigned short Bs[128 * 64];

    const int tid  = threadIdx.x;
    const int row0 = blockIdx.y * 128;
    const int col0 = blockIdx.x * 128;
    const int lane = tid & 63;
    const int wave = tid >> 6;
    const int wm = wave >> 1, wn = wave & 1;
    const int q = lane >> 4, r = lane & 15;

    f32x4 acc[4][4] = {};

    for (int k0 = 0; k0 < KT; k0 += 64) {
        #pragma unroll
        for (int ii = 0; ii < 8; ++ii) {
            const int s  = tid + ii * 256;
            const int rw = s >> 4, c4 = s & 15;
            const int ch = c4 >> 1, hf = c4 & 1;
            const int ps = ((ch + rw) & 7) * 8 + hf * 4;
            float4 v = *(const float4*)(Af32 + (size_t)(row0 + rw) * KT + k0 + c4 * 4);
            ushort4v oa;
            oa[0] = f32_bf16(v.x); oa[1] = f32_bf16(v.y);
            oa[2] = f32_bf16(v.z); oa[3] = f32_bf16(v.w);
            *(ushort4v*)(As + rw * 64 + ps) = oa;
            int4 w4 = *(const int4*)(Wi32 + (size_t)(col0 + rw) * KT + k0 + c4 * 4);
            ushort4v ob;
            ob[0] = f32_bf16((float)w4.x); ob[1] = f32_bf16((float)w4.y);
            ob[2] = f32_bf16((float)w4.z); ob[3] = f32_bf16((float)w4.w);
            *(ushort4v*)(Bs + rw * 64 + ps) = ob;
        }
        __syncthreads();
        #pragma unroll
        for (int h = 0; h < 2; ++h) {
            short8 a[4], b[4];
            #pragma unroll
            for (int i = 0; i < 4; ++i)
                a[i] = *(const short8*)(As + swzf(wm * 64 + i * 16 + r, h * 4 + q) * 8);
            #pragma unroll
            for (int j = 0; j < 4; ++j)
                b[j] = *(const short8*)(Bs + swzf(wn * 64 + j * 16 + r, h * 4 + q) * 8);
            #pragma unroll
            for (int i = 0; i < 4; ++i)
                #pragma unroll
                for (int j = 0; j < 4; ++j)
                    acc[i][j] = __builtin_amdgcn_mfma_f32_16x16x32_bf16(a[i], b[j], acc[i][j], 0, 0, 0);
        }
        __syncthreads();
    }

    #pragma unroll
    for (int j = 0; j < 4; ++j) {
        const int n  = col0 + wn * 64 + j * 16 + r;
        const float sc = ldexpf(1.0f, sexp[n]);
        const float bs = bias[n];
        #pragma unroll
        for (int i = 0; i < 4; ++i) {
            const int m = row0 + wm * 64 + i * 16 + q * 4;
            float* cp = C + (size_t)m * NT + n;
            #pragma unroll
            for (int t = 0; t < 4; ++t)
                cp[(size_t)t * NT] = acc[i][j][t] * sc + bs;
        }
    }
}

extern "C" void kernel_launch(void* const* d_in, const int* in_sizes, int n_in,
                              void* d_out, int out_size, void* d_ws, size_t ws_size,
                              hipStream_t stream) {
    const float* x    = (const float*)d_in[0];
    const int*   wq   = (const int*)d_in[1];   // ternary {-1,0,1}, int32 per harness
    const int*   se   = (const int*)d_in[2];   // exponents [-8,0]
    const float* bias = (const float*)d_in[3];
    float* out = (float*)d_out;

    const size_t xb_elems = (size_t)MT * KT;   // 33554432
    const size_t wb_elems = (size_t)NT * KT;   // 4194304

    if (ws_size >= (xb_elems + wb_elems) * sizeof(unsigned short)) {
        unsigned short* xb = (unsigned short*)d_ws;
        unsigned short* wb = xb + xb_elems;
        cvt_kernel<<<(int)((xb_elems + wb_elems) / (256 * 8)), 256, 0, stream>>>(x, wq, xb, wb);
        dim3 grid(NT / BN, MT / BM);           // (8, 64): bn fast == XCD id, B-slab L2-resident
        gemm_8ph<<<grid, THREADS, 0, stream>>>(xb, wb, se, bias, out);
    } else {
        dim3 fgrid(NT / 128, MT / 128);        // (16, 128)
        gemm_fb<<<fgrid, 256, 0, stream>>>(x, wq, se, bias, out);
    }
}

// Round 4
// 370.011 us; speedup vs baseline: 1.0862x; 1.0862x over previous
//
#include <hip/hip_runtime.h>

#define MT 16384   // B*T = 8*2048
#define NT 2048    // OUT
#define KT 2048    // IN
#define BM 256
#define BN 256
#define BK 64
#define NKT (KT / BK)    // 32 K-tiles
#define THREADS 512

typedef __attribute__((ext_vector_type(8))) short short8;     // 8 bf16 (4 VGPRs) MFMA A/B frag
typedef __attribute__((ext_vector_type(4))) float f32x4;      // MFMA C/D frag
typedef __attribute__((ext_vector_type(8))) unsigned short ushort8;
typedef __attribute__((ext_vector_type(4))) unsigned short ushort4v;

__device__ __forceinline__ unsigned short f32_bf16(float f) {
    union { float f; unsigned u; } v; v.f = f;
    return (unsigned short)((v.u + 0x7FFFu + ((v.u >> 16) & 1u)) >> 16);
}

// ---- merged preconvert: x (fp32->bf16) then w (int32->bf16), one dispatch ----

__global__ __launch_bounds__(256) void cvt_kernel(const float* __restrict__ x,
                                                  const int* __restrict__ w,
                                                  unsigned short* __restrict__ xb,
                                                  unsigned short* __restrict__ wb) {
    const int b = blockIdx.x;
    if (b < MT * KT / 2048) {
        size_t i = ((size_t)b * 256 + threadIdx.x) * 8;
        float4 v0 = *(const float4*)(x + i);
        float4 v1 = *(const float4*)(x + i + 4);
        ushort8 o;
        o[0] = f32_bf16(v0.x); o[1] = f32_bf16(v0.y); o[2] = f32_bf16(v0.z); o[3] = f32_bf16(v0.w);
        o[4] = f32_bf16(v1.x); o[5] = f32_bf16(v1.y); o[6] = f32_bf16(v1.z); o[7] = f32_bf16(v1.w);
        *(ushort8*)(xb + i) = o;
    } else {
        size_t i = ((size_t)(b - MT * KT / 2048) * 256 + threadIdx.x) * 8;
        int4 v0 = *(const int4*)(w + i);
        int4 v1 = *(const int4*)(w + i + 4);
        ushort8 o;
        o[0] = f32_bf16((float)v0.x); o[1] = f32_bf16((float)v0.y);
        o[2] = f32_bf16((float)v0.z); o[3] = f32_bf16((float)v0.w);
        o[4] = f32_bf16((float)v1.x); o[5] = f32_bf16((float)v1.y);
        o[6] = f32_bf16((float)v1.z); o[7] = f32_bf16((float)v1.w);
        *(ushort8*)(wb + i) = o;
    }
}

// ---- R10: R7 geometry (8-phase-per-2-tiles, 16x16x32, rotation swizzle) with
//      kh-SPLIT phase decomposition to de-cluster the phase-0 B reads ----
//
// R8/R9 (32x32 shape) both regressed via unexplained LDS bank conflicts on the
// row=lane&31 read pattern; reverted. This kernel keeps R7's VERIFIED-zero-
// conflict per-instruction read pattern: row = base + (lane&15), chunk
// c = kh*4 + (lane>>4), slot = (c + row) & 7, bytes = row*128 + slot*16.
//
// Phase decomposition (per K-tile, per wave 128x64 = 8 f-blocks x 4 j x 2 kh):
//   ph0: ldA f0-3 kh0 (4 rd) + ldB kh0 (4 rd); mma f0-3 x j x kh0  (16 MFMA)
//   ph1: ldA f4-7 kh0 (4 rd);                  mma f4-7 x j x kh0
//   ph2: ldA f0-3 kh1 (4 rd) + ldB kh1 (4 rd); mma f0-3 x j x kh1
//   ph3: ldA f4-7 kh1 (4 rd);                  mma f4-7 x j x kh1
// f-block g = 2f + wm -> f0-3 = A rows 0-127 (h0), f4-7 = rows 128-255 (h1).
// Last-read: A-h0 @ ph2, A-h1 @ ph3, B @ ph2.
//
// Stage rotation (every stage targets slots freed at a STRICTLY earlier,
// barrier-separated phase):
//   ph0: A(t+1)h1 [2 loads]  (slot = buf^1 A-h1, last read at tile t-1 ph3)
//   ph3: B(t+2)h0 + B(t+2)h1 + A(t+2)h0 [6 loads]
//        (slots = current buf's B (freed after ph2) and A-h0 (freed after ph2))
//   vmcnt(6) at end of ph3: leaves exactly the three t+2 half-tiles in
//   flight; A(t+1)h1 (issued ph0) and everything older drained -> tile t+1
//   fully present at its entry barrier.
// LDS: [2 buf][256 rows][8 slots of 16B]; logical (row,c) at slot (c+row)&7;
// global_load_lds source pre-swizzled, LDS dest linear (m104/m173).

__global__ __launch_bounds__(THREADS, 2) void gemm_8ph(
    const unsigned short* __restrict__ Abf, const unsigned short* __restrict__ Bbf,
    const int* __restrict__ sexp, const float* __restrict__ bias,
    float* __restrict__ C)
{
    __shared__ unsigned short As[2 * 2048 * 8];   // 64 KB: [buf][256 rows][8 slots][8 bf16]
    __shared__ unsigned short Bs[2 * 2048 * 8];   // 64 KB

    const int tid  = threadIdx.x;
    const int bn   = blockIdx.x;            // N block; bn == XCD id (8 exact): B-slab L2-resident
    const int bm   = blockIdx.y;
    const int brow0 = bm * BM;
    const int bcol0 = bn * BN;
    const int lane = tid & 63;
    const int wave = tid >> 6;
    const int wm = wave >> 2;               // 0..1  (M, interleaved 16-row blocks 2f+wm)
    const int wn = wave & 3;                // 0..3  (N, contiguous 64-col stripe)
    const int q = lane >> 4, r = lane & 15;

    // staging source offsets (ushort units) per (half, ii): slot s = h*1024+ii*512+tid
    // holds logical chunk ((s&7)-row)&7 of row s>>3 (inverse of the read swizzle).
    size_t aoff[2][2], boff[2][2];
    #pragma unroll
    for (int h = 0; h < 2; ++h)
        #pragma unroll
        for (int ii = 0; ii < 2; ++ii) {
            const int s   = h * 1024 + ii * 512 + tid;
            const int row = s >> 3;
            const int cg  = ((s & 7) - row) & 7;
            aoff[h][ii] = (size_t)(brow0 + row) * KT + cg * 8;
            boff[h][ii] = (size_t)(bcol0 + row) * KT + cg * 8;
        }

#define GLDS(srcp, dstp)                                                            \
    __builtin_amdgcn_global_load_lds(                                               \
        (const __attribute__((address_space(1))) unsigned int*)(srcp),              \
        (__attribute__((address_space(3))) unsigned int*)(dstp), 16, 0, 0)

    auto stageA = [&](int tile, int h) {
        const int buf = tile & 1;
        const size_t k = (size_t)tile * BK;
        GLDS(Abf + aoff[h][0] + k, As + buf * 16384 + (h * 1024 + wave * 64) * 8);
        GLDS(Abf + aoff[h][1] + k, As + buf * 16384 + (h * 1024 + 512 + wave * 64) * 8);
    };
    auto stageB = [&](int tile, int h) {
        const int buf = tile & 1;
        const size_t k = (size_t)tile * BK;
        GLDS(Bbf + boff[h][0] + k, Bs + buf * 16384 + (h * 1024 + wave * 64) * 8);
        GLDS(Bbf + boff[h][1] + k, Bs + buf * 16384 + (h * 1024 + 512 + wave * 64) * 8);
    };

    f32x4 acc[8][4] = {};
    short8 a[4];   // current phase's 4 A-frags (f-quad x current kh)
    short8 b[4];   // current kh's 4 B-frags (read at ph0/ph2, held 2 phases)

    auto ldA = [&](int buf, int fq, int kh) {
        const unsigned short* base = As + buf * 16384;
        #pragma unroll
        for (int u = 0; u < 4; ++u) {
            const int row = (2 * (fq * 4 + u) + wm) * 16 + r;       // g = 2f + wm
            a[u] = *(const short8*)(base + row * 64 + ((kh * 4 + q + row) & 7) * 8);
        }
    };
    auto ldB = [&](int buf, int kh) {
        const unsigned short* base = Bs + buf * 16384;
        #pragma unroll
        for (int j = 0; j < 4; ++j) {
            const int row = wn * 64 + j * 16 + r;
            b[j] = *(const short8*)(base + row * 64 + ((kh * 4 + q + row) & 7) * 8);
        }
    };
    auto mma = [&](int fq) {
        #pragma unroll
        for (int u = 0; u < 4; ++u)
            #pragma unroll
            for (int j = 0; j < 4; ++j)
                acc[fq * 4 + u][j] = __builtin_amdgcn_mfma_f32_16x16x32_bf16(
                    a[u], b[j], acc[fq * 4 + u][j], 0, 0, 0);
    };

#define PHASE(buf, fq, kh, STAGE_STMT, WAIT_STMT) do {     \
        ldA(buf, fq, kh);                                  \
        if ((fq) == 0) ldB(buf, kh);                       \
        STAGE_STMT;                                        \
        __builtin_amdgcn_s_barrier();                      \
        asm volatile("s_waitcnt lgkmcnt(0)");              \
        __builtin_amdgcn_sched_barrier(0);                 \
        __builtin_amdgcn_s_setprio(1);                     \
        mma(fq);                                           \
        __builtin_amdgcn_s_setprio(0);                     \
        WAIT_STMT;                                         \
        __builtin_amdgcn_s_barrier();                      \
    } while (0)

#define TILE(buf, t, PH0_STAGE, PH3_STAGE, PH3_WAIT) do {  \
        PHASE(buf, 0, 0, PH0_STAGE, (void)0);              \
        PHASE(buf, 1, 0, (void)0,   (void)0);              \
        PHASE(buf, 0, 1, (void)0,   (void)0);              \
        PHASE(buf, 1, 1, PH3_STAGE, PH3_WAIT);             \
    } while (0)

    // prologue: tile0 fully (8 loads) + tile1's {Bh0, Bh1, Ah0} (6 loads);
    // vmcnt(6) -> tile0 landed, 3 half-tiles of tile1 in flight; barrier publishes.
    stageB(0, 0); stageB(0, 1); stageA(0, 0); stageA(0, 1);
    stageB(1, 0); stageB(1, 1); stageA(1, 0);
    asm volatile("s_waitcnt vmcnt(6)" ::: "memory");
    __builtin_amdgcn_s_barrier();

    #pragma unroll 1
    for (int i = 0; i < 15; ++i) {                 // tiles 0..29
        const int t0 = 2 * i, t1 = 2 * i + 1;
        TILE(0, t0,
             { stageA(t0 + 1, 1); },
             { stageB(t0 + 2, 0); stageB(t0 + 2, 1); stageA(t0 + 2, 0); },
             asm volatile("s_waitcnt vmcnt(6)" ::: "memory"));
        TILE(1, t1,
             { stageA(t1 + 1, 1); },
             { stageB(t1 + 2, 0); stageB(t1 + 2, 1); stageA(t1 + 2, 0); },
             asm volatile("s_waitcnt vmcnt(6)" ::: "memory"));
    }

    // tile 30 (buf 0): ph0 stages A(31)h1; no ph3 stages; drain to 0 so tile 31 complete.
    TILE(0, 30,
         { stageA(31, 1); },
         (void)0,
         asm volatile("s_waitcnt vmcnt(0)" ::: "memory"));
    // tile 31 (buf 1): no stages, no waits.
    TILE(1, 31, (void)0, (void)0, (void)0);

#undef TILE
#undef PHASE
#undef GLDS

    // epilogue: C/D layout col = lane&15, row = (lane>>4)*4 + reg  [m89/m91-verified]
    // f-th M-frag sits at global 16-row block (2f + wm)  (interleaved mapping)
    #pragma unroll
    for (int j = 0; j < 4; ++j) {
        const int n  = bcol0 + wn * 64 + j * 16 + r;
        const float sc = ldexpf(1.0f, sexp[n]);   // exact power-of-two scale
        const float bs = bias[n];
        #pragma unroll
        for (int f = 0; f < 8; ++f) {
            const int m = brow0 + (2 * f + wm) * 16 + q * 4;
            float* cp = C + (size_t)m * NT + n;
            #pragma unroll
            for (int t = 0; t < 4; ++t)
                cp[(size_t)t * NT] = acc[f][j][t] * sc + bs;
        }
    }
}

// ---- fallback (no workspace): old verified fused 128x128 kernel ----

__device__ __forceinline__ int swzf(int row, int c) { return row * 8 + ((c + row) & 7); }

__global__ __launch_bounds__(256) void gemm_fb(
    const float* __restrict__ Af32, const int* __restrict__ Wi32,
    const int* __restrict__ sexp, const float* __restrict__ bias,
    float* __restrict__ C)
{
    __shared__ unsigned short As[128 * 64];
    __shared__ unsigned short Bs[128 * 64];

    const int tid  = threadIdx.x;
    const int row0 = blockIdx.y * 128;
    const int col0 = blockIdx.x * 128;
    const int lane = tid & 63;
    const int wave = tid >> 6;
    const int wm = wave >> 1, wn = wave & 1;
    const int q = lane >> 4, r = lane & 15;

    f32x4 acc[4][4] = {};

    for (int k0 = 0; k0 < KT; k0 += 64) {
        #pragma unroll
        for (int ii = 0; ii < 8; ++ii) {
            const int s  = tid + ii * 256;
            const int rw = s >> 4, c4 = s & 15;
            const int ch = c4 >> 1, hf = c4 & 1;
            const int ps = ((ch + rw) & 7) * 8 + hf * 4;
            float4 v = *(const float4*)(Af32 + (size_t)(row0 + rw) * KT + k0 + c4 * 4);
            ushort4v oa;
            oa[0] = f32_bf16(v.x); oa[1] = f32_bf16(v.y);
            oa[2] = f32_bf16(v.z); oa[3] = f32_bf16(v.w);
            *(ushort4v*)(As + rw * 64 + ps) = oa;
            int4 w4 = *(const int4*)(Wi32 + (size_t)(col0 + rw) * KT + k0 + c4 * 4);
            ushort4v ob;
            ob[0] = f32_bf16((float)w4.x); ob[1] = f32_bf16((float)w4.y);
            ob[2] = f32_bf16((float)w4.z); ob[3] = f32_bf16((float)w4.w);
            *(ushort4v*)(Bs + rw * 64 + ps) = ob;
        }
        __syncthreads();
        #pragma unroll
        for (int h = 0; h < 2; ++h) {
            short8 a[4], b[4];
            #pragma unroll
            for (int i = 0; i < 4; ++i)
                a[i] = *(const short8*)(As + swzf(wm * 64 + i * 16 + r, h * 4 + q) * 8);
            #pragma unroll
            for (int j = 0; j < 4; ++j)
                b[j] = *(const short8*)(Bs + swzf(wn * 64 + j * 16 + r, h * 4 + q) * 8);
            #pragma unroll
            for (int i = 0; i < 4; ++i)
                #pragma unroll
                for (int j = 0; j < 4; ++j)
                    acc[i][j] = __builtin_amdgcn_mfma_f32_16x16x32_bf16(a[i], b[j], acc[i][j], 0, 0, 0);
        }
        __syncthreads();
    }

    #pragma unroll
    for (int j = 0; j < 4; ++j) {
        const int n  = col0 + wn * 64 + j * 16 + r;
        const float sc = ldexpf(1.0f, sexp[n]);
        const float bs = bias[n];
        #pragma unroll
        for (int i = 0; i < 4; ++i) {
            const int m = row0 + wm * 64 + i * 16 + q * 4;
            float* cp = C + (size_t)m * NT + n;
            #pragma unroll
            for (int t = 0; t < 4; ++t)
                cp[(size_t)t * NT] = acc[i][j][t] * sc + bs;
        }
    }
}

extern "C" void kernel_launch(void* const* d_in, const int* in_sizes, int n_in,
                              void* d_out, int out_size, void* d_ws, size_t ws_size,
                              hipStream_t stream) {
    const float* x    = (const float*)d_in[0];
    const int*   wq   = (const int*)d_in[1];   // ternary {-1,0,1}, int32 per harness
    const int*   se   = (const int*)d_in[2];   // exponents [-8,0]
    const float* bias = (const float*)d_in[3];
    float* out = (float*)d_out;

    const size_t xb_elems = (size_t)MT * KT;   // 33554432
    const size_t wb_elems = (size_t)NT * KT;   // 4194304

    if (ws_size >= (xb_elems + wb_elems) * sizeof(unsigned short)) {
        unsigned short* xb = (unsigned short*)d_ws;
        unsigned short* wb = xb + xb_elems;
        cvt_kernel<<<(int)((xb_elems + wb_elems) / (256 * 8)), 256, 0, stream>>>(x, wq, xb, wb);
        dim3 grid(NT / BN, MT / BM);           // (8, 64): bn fast == XCD id, B-slab L2-resident
        gemm_8ph<<<grid, THREADS, 0, stream>>>(xb, wb, se, bias, out);
    } else {
        dim3 fgrid(NT / 128, MT / 128);        // (16, 128)
        gemm_fb<<<fgrid, 256, 0, stream>>>(x, wq, se, bias, out);
    }
}

// Round 5
// 366.880 us; speedup vs baseline: 1.0954x; 1.0085x over previous
//
#include <hip/hip_runtime.h>

#define MT 16384   // B*T = 8*2048
#define NT 2048    // OUT
#define KT 2048    // IN
#define BM 256
#define BN 256
#define BK 64
#define NKT (KT / BK)    // 32 K-tiles
#define THREADS 512

typedef __attribute__((ext_vector_type(8))) short short8;     // 8 bf16 (4 VGPRs) MFMA A/B frag
typedef __attribute__((ext_vector_type(4))) float f32x4;      // MFMA C/D frag
typedef __attribute__((ext_vector_type(8))) unsigned short ushort8;
typedef __attribute__((ext_vector_type(4))) unsigned short ushort4v;

__device__ __forceinline__ unsigned short f32_bf16(float f) {
    union { float f; unsigned u; } v; v.f = f;
    return (unsigned short)((v.u + 0x7FFFu + ((v.u >> 16) & 1u)) >> 16);
}

// ---- merged preconvert: x (fp32->bf16) then w (int32->bf16), one dispatch ----

__global__ __launch_bounds__(256) void cvt_kernel(const float* __restrict__ x,
                                                  const int* __restrict__ w,
                                                  unsigned short* __restrict__ xb,
                                                  unsigned short* __restrict__ wb) {
    const int b = blockIdx.x;
    if (b < MT * KT / 2048) {
        size_t i = ((size_t)b * 256 + threadIdx.x) * 8;
        float4 v0 = *(const float4*)(x + i);
        float4 v1 = *(const float4*)(x + i + 4);
        ushort8 o;
        o[0] = f32_bf16(v0.x); o[1] = f32_bf16(v0.y); o[2] = f32_bf16(v0.z); o[3] = f32_bf16(v0.w);
        o[4] = f32_bf16(v1.x); o[5] = f32_bf16(v1.y); o[6] = f32_bf16(v1.z); o[7] = f32_bf16(v1.w);
        *(ushort8*)(xb + i) = o;
    } else {
        size_t i = ((size_t)(b - MT * KT / 2048) * 256 + threadIdx.x) * 8;
        int4 v0 = *(const int4*)(w + i);
        int4 v1 = *(const int4*)(w + i + 4);
        ushort8 o;
        o[0] = f32_bf16((float)v0.x); o[1] = f32_bf16((float)v0.y);
        o[2] = f32_bf16((float)v0.z); o[3] = f32_bf16((float)v0.w);
        o[4] = f32_bf16((float)v1.x); o[5] = f32_bf16((float)v1.y);
        o[6] = f32_bf16((float)v1.z); o[7] = f32_bf16((float)v1.w);
        *(ushort8*)(wb + i) = o;
    }
}

// ---- R11: faithful m201 quadrant schedule on the R7 skeleton ----
//
// R7=150us (12/4/4/4 reads, B reloaded); R8/R9 (32x32) and R10 (kh-split) all
// regressed. This round ports the template's QUADRANT phase order with held-B:
//   P0: Q(f0-3, b0): ldA fq0 (8 rd) + ldB b0 (4 rd) = 12 rd, lgkmcnt(8) hint
//   P1: Q(f0-3, b1): ldB b1 (4 rd)                  (af reused)
//   P2: Q(f4-7, b1): ldA fq1 (8 rd)                 (bf1 reused)
//   P3: Q(f4-7, b0): 0 rd                           (af + bf0 reused)
// Each phase: 16 MFMA (4 u x 2 v x 2 kh). P3 has NO lgkm dependency -> its
// MFMA cluster issues immediately, covering other waves' LDS drain.
//
// M mapping INTERLEAVED (wave wm owns 16-row blocks 2f+wm): f0-3 = LDS A
// rows 0-127 (h0), f4-7 = h1. N-quadrants: b0 = wave cols 0-31, b1 = 32-63;
// B LDS halves are fully read after P1. LDS slot free-times: A-h0@P0,
// A-h1@P2, B-*@P1 -> stage rotation (each stage hits a slot freed at a
// strictly earlier, barrier-separated phase):
//   P0: A(t+1)h1   [buf^1 A-h1 last read at t-1 P2]
//   P1: A(t+2)h0   [current-buf A-h0 last read at THIS tile's P0]
//   P2: B(t+2)h0   [current-buf B free after P1]
//   P3: B(t+2)h1   [same] + vmcnt(6)
// vmcnt(6)@P3 keeps exactly {A(t+2)h0, B(t+2)h0, B(t+2)h1} in flight and
// drains A(t+1)h1 + all of tile t+1's older pieces -> tile t+1 fully landed
// at entry. Read pattern per instruction identical to R7 (verified 0-conflict):
// row = base + (lane&15), chunk c = kh*4 + (lane>>4), slot = (c+row)&7.
// LDS: [2 buf][256 rows][8 slots of 16B]; global_load_lds source pre-swizzled,
// LDS dest linear (m104/m173).

__global__ __launch_bounds__(THREADS, 2) void gemm_8ph(
    const unsigned short* __restrict__ Abf, const unsigned short* __restrict__ Bbf,
    const int* __restrict__ sexp, const float* __restrict__ bias,
    float* __restrict__ C)
{
    __shared__ unsigned short As[2 * 2048 * 8];   // 64 KB: [buf][256 rows][8 slots][8 bf16]
    __shared__ unsigned short Bs[2 * 2048 * 8];   // 64 KB

    const int tid  = threadIdx.x;
    const int bn   = blockIdx.x;            // N block; bn == XCD id (8 exact): B-slab L2-resident
    const int bm   = blockIdx.y;
    const int brow0 = bm * BM;
    const int bcol0 = bn * BN;
    const int lane = tid & 63;
    const int wave = tid >> 6;
    const int wm = wave >> 2;               // 0..1  (M, interleaved 16-row blocks 2f+wm)
    const int wn = wave & 3;                // 0..3  (N, contiguous 64-col stripe)
    const int q = lane >> 4, r = lane & 15;

    // staging source offsets (ushort units) per (half, ii): slot s = h*1024+ii*512+tid
    // holds logical chunk ((s&7)-row)&7 of row s>>3 (inverse of the read swizzle).
    size_t aoff[2][2], boff[2][2];
    #pragma unroll
    for (int h = 0; h < 2; ++h)
        #pragma unroll
        for (int ii = 0; ii < 2; ++ii) {
            const int s   = h * 1024 + ii * 512 + tid;
            const int row = s >> 3;
            const int cg  = ((s & 7) - row) & 7;
            aoff[h][ii] = (size_t)(brow0 + row) * KT + cg * 8;
            boff[h][ii] = (size_t)(bcol0 + row) * KT + cg * 8;
        }

#define GLDS(srcp, dstp)                                                            \
    __builtin_amdgcn_global_load_lds(                                               \
        (const __attribute__((address_space(1))) unsigned int*)(srcp),              \
        (__attribute__((address_space(3))) unsigned int*)(dstp), 16, 0, 0)

    auto stageA = [&](int tile, int h) {
        const int buf = tile & 1;
        const size_t k = (size_t)tile * BK;
        GLDS(Abf + aoff[h][0] + k, As + buf * 16384 + (h * 1024 + wave * 64) * 8);
        GLDS(Abf + aoff[h][1] + k, As + buf * 16384 + (h * 1024 + 512 + wave * 64) * 8);
    };
    auto stageB = [&](int tile, int h) {
        const int buf = tile & 1;
        const size_t k = (size_t)tile * BK;
        GLDS(Bbf + boff[h][0] + k, Bs + buf * 16384 + (h * 1024 + wave * 64) * 8);
        GLDS(Bbf + boff[h][1] + k, Bs + buf * 16384 + (h * 1024 + 512 + wave * 64) * 8);
    };

    f32x4 acc[8][4] = {};
    short8 af[4][2];    // current f-quad's A frags (loaded P0 / P2, reused next phase)
    short8 bf0[2][2];   // b0 (wave cols 0-31): loaded P0, used P0 and P3
    short8 bf1[2][2];   // b1 (wave cols 32-63): loaded P1, used P1 and P2

    auto ldA = [&](int buf, int fq) {
        const unsigned short* base = As + buf * 16384;
        #pragma unroll
        for (int u = 0; u < 4; ++u) {
            const int row = (2 * (fq * 4 + u) + wm) * 16 + r;   // g = 2f + wm
            #pragma unroll
            for (int kh = 0; kh < 2; ++kh)
                af[u][kh] = *(const short8*)(base + row * 64 + ((kh * 4 + q + row) & 7) * 8);
        }
    };
    auto ldB = [&](int buf, int bh, short8 (&bf)[2][2]) {
        const unsigned short* base = Bs + buf * 16384;
        #pragma unroll
        for (int v = 0; v < 2; ++v) {
            const int row = wn * 64 + (bh * 2 + v) * 16 + r;
            #pragma unroll
            for (int kh = 0; kh < 2; ++kh)
                bf[v][kh] = *(const short8*)(base + row * 64 + ((kh * 4 + q + row) & 7) * 8);
        }
    };
    auto mma = [&](int fq, int bh, short8 (&bf)[2][2]) {
        #pragma unroll
        for (int u = 0; u < 4; ++u)
            #pragma unroll
            for (int v = 0; v < 2; ++v)
                #pragma unroll
                for (int kh = 0; kh < 2; ++kh)
                    acc[fq * 4 + u][bh * 2 + v] = __builtin_amdgcn_mfma_f32_16x16x32_bf16(
                        af[u][kh], bf[v][kh], acc[fq * 4 + u][bh * 2 + v], 0, 0, 0);
    };

#define BARRIER()   __builtin_amdgcn_s_barrier()
#define LGKM0()     do { asm volatile("s_waitcnt lgkmcnt(0)");                 \
                         __builtin_amdgcn_sched_barrier(0); } while (0)
#define PRIO(x)     __builtin_amdgcn_s_setprio(x)

#define TILE(buf, S0, S1, S2, S3, W3) do {                                     \
        /* P0: Q(fq0,b0), 12 reads */                                          \
        ldA(buf, 0); ldB(buf, 0, bf0);                                         \
        S0;                                                                    \
        asm volatile("s_waitcnt lgkmcnt(8)");  /* pacing hint (template) */    \
        BARRIER(); LGKM0();                                                    \
        PRIO(1); mma(0, 0, bf0); PRIO(0);                                      \
        BARRIER();                                                             \
        /* P1: Q(fq0,b1), 4 reads */                                           \
        ldB(buf, 1, bf1);                                                      \
        S1;                                                                    \
        BARRIER(); LGKM0();                                                    \
        PRIO(1); mma(0, 1, bf1); PRIO(0);                                      \
        BARRIER();                                                             \
        /* P2: Q(fq1,b1), 8 reads */                                           \
        ldA(buf, 1);                                                           \
        S2;                                                                    \
        BARRIER(); LGKM0();                                                    \
        PRIO(1); mma(1, 1, bf1); PRIO(0);                                      \
        BARRIER();                                                             \
        /* P3: Q(fq1,b0), 0 reads -> MFMA issues with no lgkm dependency */    \
        S3;                                                                    \
        BARRIER();                                                             \
        PRIO(1); mma(1, 0, bf0); PRIO(0);                                      \
        W3;                                                                    \
        BARRIER();                                                             \
    } while (0)

    // prologue: tile0 fully (8 loads) + {A(1)h0, B(1)h0, B(1)h1} (6 loads);
    // vmcnt(6) drains tile0, leaves exactly the steady-state in-flight trio.
    // A(1)h1 is staged at tile0's P0 per the rotation.
    stageA(0, 0); stageA(0, 1); stageB(0, 0); stageB(0, 1);
    stageA(1, 0); stageB(1, 0); stageB(1, 1);
    asm volatile("s_waitcnt vmcnt(6)" ::: "memory");
    __builtin_amdgcn_s_barrier();

    #pragma unroll 1
    for (int i = 0; i < 15; ++i) {                 // tiles 0..29
        const int t0 = 2 * i, t1 = 2 * i + 1;
        TILE(0,
             { stageA(t0 + 1, 1); },
             { stageA(t0 + 2, 0); },
             { stageB(t0 + 2, 0); },
             { stageB(t0 + 2, 1); },
             asm volatile("s_waitcnt vmcnt(6)" ::: "memory"));
        TILE(1,
             { stageA(t1 + 1, 1); },
             { stageA(t1 + 2, 0); },
             { stageB(t1 + 2, 0); },
             { stageB(t1 + 2, 1); },
             asm volatile("s_waitcnt vmcnt(6)" ::: "memory"));
    }

    // tile 30 (buf 0): P0 stages A(31)h1 (needed); no t+2 stages; drain to 0
    // so tile 31's pieces (A31h0 @t29P1, B31 @t29P2/P3, A31h1 @t30P0) land.
    TILE(0,
         { stageA(31, 1); },
         (void)0, (void)0, (void)0,
         asm volatile("s_waitcnt vmcnt(0)" ::: "memory"));
    // tile 31 (buf 1): no stages, no waits.
    TILE(1, (void)0, (void)0, (void)0, (void)0, (void)0);

#undef TILE
#undef PRIO
#undef LGKM0
#undef BARRIER
#undef GLDS

    // epilogue: C/D layout col = lane&15, row = (lane>>4)*4 + reg  [m89/m91-verified]
    // f-th M-frag at global 16-row block (2f + wm); j = bh*2+v -> col block j.
    #pragma unroll
    for (int j = 0; j < 4; ++j) {
        const int n  = bcol0 + wn * 64 + j * 16 + r;
        const float sc = ldexpf(1.0f, sexp[n]);   // exact power-of-two scale
        const float bs = bias[n];
        #pragma unroll
        for (int f = 0; f < 8; ++f) {
            const int m = brow0 + (2 * f + wm) * 16 + q * 4;
            float* cp = C + (size_t)m * NT + n;
            #pragma unroll
            for (int t = 0; t < 4; ++t)
                cp[(size_t)t * NT] = acc[f][j][t] * sc + bs;
        }
    }
}

// ---- fallback (no workspace): old verified fused 128x128 kernel ----

__device__ __forceinline__ int swzf(int row, int c) { return row * 8 + ((c + row) & 7); }

__global__ __launch_bounds__(256) void gemm_fb(
    const float* __restrict__ Af32, const int* __restrict__ Wi32,
    const int* __restrict__ sexp, const float* __restrict__ bias,
    float* __restrict__ C)
{
    __shared__ unsigned short As[128 * 64];
    __shared__ unsigned short Bs[128 * 64];

    const int tid  = threadIdx.x;
    const int row0 = blockIdx.y * 128;
    const int col0 = blockIdx.x * 128;
    const int lane = tid & 63;
    const int wave = tid >> 6;
    const int wm = wave >> 1, wn = wave & 1;
    const int q = lane >> 4, r = lane & 15;

    f32x4 acc[4][4] = {};

    for (int k0 = 0; k0 < KT; k0 += 64) {
        #pragma unroll
        for (int ii = 0; ii < 8; ++ii) {
            const int s  = tid + ii * 256;
            const int rw = s >> 4, c4 = s & 15;
            const int ch = c4 >> 1, hf = c4 & 1;
            const int ps = ((ch + rw) & 7) * 8 + hf * 4;
            float4 v = *(const float4*)(Af32 + (size_t)(row0 + rw) * KT + k0 + c4 * 4);
            ushort4v oa;
            oa[0] = f32_bf16(v.x); oa[1] = f32_bf16(v.y);
            oa[2] = f32_bf16(v.z); oa[3] = f32_bf16(v.w);
            *(ushort4v*)(As + rw * 64 + ps) = oa;
            int4 w4 = *(const int4*)(Wi32 + (size_t)(col0 + rw) * KT + k0 + c4 * 4);
            ushort4v ob;
            ob[0] = f32_bf16((float)w4.x); ob[1] = f32_bf16((float)w4.y);
            ob[2] = f32_bf16((float)w4.z); ob[3] = f32_bf16((float)w4.w);
            *(ushort4v*)(Bs + rw * 64 + ps) = ob;
        }
        __syncthreads();
        #pragma unroll
        for (int h = 0; h < 2; ++h) {
            short8 a[4], b[4];
            #pragma unroll
            for (int i = 0; i < 4; ++i)
                a[i] = *(const short8*)(As + swzf(wm * 64 + i * 16 + r, h * 4 + q) * 8);
            #pragma unroll
            for (int j = 0; j < 4; ++j)
                b[j] = *(const short8*)(Bs + swzf(wn * 64 + j * 16 + r, h * 4 + q) * 8);
            #pragma unroll
            for (int i = 0; i < 4; ++i)
                #pragma unroll
                for (int j = 0; j < 4; ++j)
                    acc[i][j] = __builtin_amdgcn_mfma_f32_16x16x32_bf16(a[i], b[j], acc[i][j], 0, 0, 0);
        }
        __syncthreads();
    }

    #pragma unroll
    for (int j = 0; j < 4; ++j) {
        const int n  = col0 + wn * 64 + j * 16 + r;
        const float sc = ldexpf(1.0f, sexp[n]);
        const float bs = bias[n];
        #pragma unroll
        for (int i = 0; i < 4; ++i) {
            const int m = row0 + wm * 64 + i * 16 + q * 4;
            float* cp = C + (size_t)m * NT + n;
            #pragma unroll
            for (int t = 0; t < 4; ++t)
                cp[(size_t)t * NT] = acc[i][j][t] * sc + bs;
        }
    }
}

extern "C" void kernel_launch(void* const* d_in, const int* in_sizes, int n_in,
                              void* d_out, int out_size, void* d_ws, size_t ws_size,
                              hipStream_t stream) {
    const float* x    = (const float*)d_in[0];
    const int*   wq   = (const int*)d_in[1];   // ternary {-1,0,1}, int32 per harness
    const int*   se   = (const int*)d_in[2];   // exponents [-8,0]
    const float* bias = (const float*)d_in[3];
    float* out = (float*)d_out;

    const size_t xb_elems = (size_t)MT * KT;   // 33554432
    const size_t wb_elems = (size_t)NT * KT;   // 4194304

    if (ws_size >= (xb_elems + wb_elems) * sizeof(unsigned short)) {
        unsigned short* xb = (unsigned short*)d_ws;
        unsigned short* wb = xb + xb_elems;
        cvt_kernel<<<(int)((xb_elems + wb_elems) / (256 * 8)), 256, 0, stream>>>(x, wq, xb, wb);
        dim3 grid(NT / BN, MT / BM);           // (8, 64): bn fast == XCD id, B-slab L2-resident
        gemm_8ph<<<grid, THREADS, 0, stream>>>(xb, wb, se, bias, out);
    } else {
        dim3 fgrid(NT / 128, MT / 128);        // (16, 128)
        gemm_fb<<<fgrid, 256, 0, stream>>>(x, wq, se, bias, out);
    }
}

// Round 6
// 355.784 us; speedup vs baseline: 1.1296x; 1.0312x over previous
//
#include <hip/hip_runtime.h>

#define MT 16384   // B*T = 8*2048
#define NT 2048    // OUT
#define KT 2048    // IN
#define BM 256
#define BN 256
#define BK 64
#define NKT (KT / BK)    // 32 K-tiles
#define THREADS 512

typedef __attribute__((ext_vector_type(8))) short short8;     // 8 bf16 (4 VGPRs) MFMA A/B frag
typedef __attribute__((ext_vector_type(4))) float f32x4;      // MFMA C/D frag
typedef __attribute__((ext_vector_type(8))) unsigned short ushort8;
typedef __attribute__((ext_vector_type(4))) unsigned short ushort4v;

__device__ __forceinline__ unsigned short f32_bf16(float f) {
    union { float f; unsigned u; } v; v.f = f;
    return (unsigned short)((v.u + 0x7FFFu + ((v.u >> 16) & 1u)) >> 16);
}

// ---- merged preconvert: x (fp32->bf16) then w (int32->bf16), one dispatch ----

__global__ __launch_bounds__(256) void cvt_kernel(const float* __restrict__ x,
                                                  const int* __restrict__ w,
                                                  unsigned short* __restrict__ xb,
                                                  unsigned short* __restrict__ wb) {
    const int b = blockIdx.x;
    if (b < MT * KT / 2048) {
        size_t i = ((size_t)b * 256 + threadIdx.x) * 8;
        float4 v0 = *(const float4*)(x + i);
        float4 v1 = *(const float4*)(x + i + 4);
        ushort8 o;
        o[0] = f32_bf16(v0.x); o[1] = f32_bf16(v0.y); o[2] = f32_bf16(v0.z); o[3] = f32_bf16(v0.w);
        o[4] = f32_bf16(v1.x); o[5] = f32_bf16(v1.y); o[6] = f32_bf16(v1.z); o[7] = f32_bf16(v1.w);
        *(ushort8*)(xb + i) = o;
    } else {
        size_t i = ((size_t)(b - MT * KT / 2048) * 256 + threadIdx.x) * 8;
        int4 v0 = *(const int4*)(w + i);
        int4 v1 = *(const int4*)(w + i + 4);
        ushort8 o;
        o[0] = f32_bf16((float)v0.x); o[1] = f32_bf16((float)v0.y);
        o[2] = f32_bf16((float)v0.z); o[3] = f32_bf16((float)v0.w);
        o[4] = f32_bf16((float)v1.x); o[5] = f32_bf16((float)v1.y);
        o[6] = f32_bf16((float)v1.z); o[7] = f32_bf16((float)v1.w);
        *(ushort8*)(wb + i) = o;
    }
}

// ---- R12: R11 (quadrant schedule, held-B) + XCD-chunked grid + dead-barrier cull ----
//
// R11 = 146.5us, FETCH 270 MB vs ideal 72: bn==XCD mapping put the 8 blocks
// sharing an A-strip on 8 DIFFERENT XCDs -> every XCD streams all of A
// through its private L2. Fix: chunked bijective map (HK chiplet_transform):
//   L = blockIdx.x (512 blocks, %8==0 -> bijective);  xcd = L & 7; i = L >> 3
//   bm = xcd*8 + (i>>3)   (each XCD owns 8 contiguous A-strips)
//   bn = i & 7            (fastest within chunk -> the 8 same-strip blocks
//                          are consecutive arrivals on ONE XCD, co-resident)
// Per-XCD fill becomes A ~8 MB (strip fetched ~once) + B with 4x concurrent
// reuse, vs 64 MB A-stream before.
//
// Phase structure (R11, unchanged except P3 entry barrier removed — dead:
// P3 reads no LDS, its stage targets slots freed >=2 barriers earlier, and
// every wave passed its P1 B-reads before any wave left the P2-exit barrier):
//   P0: Q(f0-3, b0): ldA fq0 (8 rd) + ldB b0 (4 rd), lgkmcnt(8) pace
//   P1: Q(f0-3, b1): ldB b1 (4 rd)
//   P2: Q(f4-7, b1): ldA fq1 (8 rd)
//   P3: Q(f4-7, b0): 0 rd (regs only)
// Stage rotation: P0: A(t+1)h1 | P1: A(t+2)h0 | P2: B(t+2)h0 | P3: B(t+2)h1
// + vmcnt(6) (keeps exactly the t+2 trio in flight; tile t+1 fully landed at
// entry). Read pattern per instruction identical to R7 (verified 0-conflict):
// row = base + (lane&15), chunk c = kh*4 + (lane>>4), slot = (c+row)&7.
// LDS: [2 buf][256 rows][8 slots of 16B]; global_load_lds source pre-swizzled,
// LDS dest linear (m104/m173).

__global__ __launch_bounds__(THREADS, 2) void gemm_8ph(
    const unsigned short* __restrict__ Abf, const unsigned short* __restrict__ Bbf,
    const int* __restrict__ sexp, const float* __restrict__ bias,
    float* __restrict__ C)
{
    __shared__ unsigned short As[2 * 2048 * 8];   // 64 KB: [buf][256 rows][8 slots][8 bf16]
    __shared__ unsigned short Bs[2 * 2048 * 8];   // 64 KB

    const int tid  = threadIdx.x;
    const int L    = blockIdx.x;            // 512 blocks, 1-D
    const int xcd  = L & 7;                 // HW round-robin XCD assignment (m09)
    const int ii_  = L >> 3;                // index within XCD chunk [0,64)
    const int bm   = xcd * 8 + (ii_ >> 3);  // 8 contiguous A-strips per XCD
    const int bn   = ii_ & 7;               // fastest: same-strip blocks co-launch
    const int brow0 = bm * BM;
    const int bcol0 = bn * BN;
    const int lane = tid & 63;
    const int wave = tid >> 6;
    const int wm = wave >> 2;               // 0..1  (M, interleaved 16-row blocks 2f+wm)
    const int wn = wave & 3;                // 0..3  (N, contiguous 64-col stripe)
    const int q = lane >> 4, r = lane & 15;

    // staging source offsets (ushort units) per (half, ii): slot s = h*1024+ii*512+tid
    // holds logical chunk ((s&7)-row)&7 of row s>>3 (inverse of the read swizzle).
    size_t aoff[2][2], boff[2][2];
    #pragma unroll
    for (int h = 0; h < 2; ++h)
        #pragma unroll
        for (int ii = 0; ii < 2; ++ii) {
            const int s   = h * 1024 + ii * 512 + tid;
            const int row = s >> 3;
            const int cg  = ((s & 7) - row) & 7;
            aoff[h][ii] = (size_t)(brow0 + row) * KT + cg * 8;
            boff[h][ii] = (size_t)(bcol0 + row) * KT + cg * 8;
        }

#define GLDS(srcp, dstp)                                                            \
    __builtin_amdgcn_global_load_lds(                                               \
        (const __attribute__((address_space(1))) unsigned int*)(srcp),              \
        (__attribute__((address_space(3))) unsigned int*)(dstp), 16, 0, 0)

    auto stageA = [&](int tile, int h) {
        const int buf = tile & 1;
        const size_t k = (size_t)tile * BK;
        GLDS(Abf + aoff[h][0] + k, As + buf * 16384 + (h * 1024 + wave * 64) * 8);
        GLDS(Abf + aoff[h][1] + k, As + buf * 16384 + (h * 1024 + 512 + wave * 64) * 8);
    };
    auto stageB = [&](int tile, int h) {
        const int buf = tile & 1;
        const size_t k = (size_t)tile * BK;
        GLDS(Bbf + boff[h][0] + k, Bs + buf * 16384 + (h * 1024 + wave * 64) * 8);
        GLDS(Bbf + boff[h][1] + k, Bs + buf * 16384 + (h * 1024 + 512 + wave * 64) * 8);
    };

    f32x4 acc[8][4] = {};
    short8 af[4][2];    // current f-quad's A frags (loaded P0 / P2, reused next phase)
    short8 bf0[2][2];   // b0 (wave cols 0-31): loaded P0, used P0 and P3
    short8 bf1[2][2];   // b1 (wave cols 32-63): loaded P1, used P1 and P2

    auto ldA = [&](int buf, int fq) {
        const unsigned short* base = As + buf * 16384;
        #pragma unroll
        for (int u = 0; u < 4; ++u) {
            const int row = (2 * (fq * 4 + u) + wm) * 16 + r;   // g = 2f + wm
            #pragma unroll
            for (int kh = 0; kh < 2; ++kh)
                af[u][kh] = *(const short8*)(base + row * 64 + ((kh * 4 + q + row) & 7) * 8);
        }
    };
    auto ldB = [&](int buf, int bh, short8 (&bf)[2][2]) {
        const unsigned short* base = Bs + buf * 16384;
        #pragma unroll
        for (int v = 0; v < 2; ++v) {
            const int row = wn * 64 + (bh * 2 + v) * 16 + r;
            #pragma unroll
            for (int kh = 0; kh < 2; ++kh)
                bf[v][kh] = *(const short8*)(base + row * 64 + ((kh * 4 + q + row) & 7) * 8);
        }
    };
    auto mma = [&](int fq, int bh, short8 (&bf)[2][2]) {
        #pragma unroll
        for (int u = 0; u < 4; ++u)
            #pragma unroll
            for (int v = 0; v < 2; ++v)
                #pragma unroll
                for (int kh = 0; kh < 2; ++kh)
                    acc[fq * 4 + u][bh * 2 + v] = __builtin_amdgcn_mfma_f32_16x16x32_bf16(
                        af[u][kh], bf[v][kh], acc[fq * 4 + u][bh * 2 + v], 0, 0, 0);
    };

#define BARRIER()   __builtin_amdgcn_s_barrier()
#define LGKM0()     do { asm volatile("s_waitcnt lgkmcnt(0)");                 \
                         __builtin_amdgcn_sched_barrier(0); } while (0)
#define PRIO(x)     __builtin_amdgcn_s_setprio(x)

#define TILE(buf, S0, S1, S2, S3, W3) do {                                     \
        /* P0: Q(fq0,b0), 12 reads */                                          \
        ldA(buf, 0); ldB(buf, 0, bf0);                                         \
        S0;                                                                    \
        asm volatile("s_waitcnt lgkmcnt(8)");  /* pacing hint (template) */    \
        BARRIER(); LGKM0();                                                    \
        PRIO(1); mma(0, 0, bf0); PRIO(0);                                      \
        BARRIER();                                                             \
        /* P1: Q(fq0,b1), 4 reads */                                           \
        ldB(buf, 1, bf1);                                                      \
        S1;                                                                    \
        BARRIER(); LGKM0();                                                    \
        PRIO(1); mma(0, 1, bf1); PRIO(0);                                      \
        BARRIER();                                                             \
        /* P2: Q(fq1,b1), 8 reads */                                           \
        ldA(buf, 1);                                                           \
        S2;                                                                    \
        BARRIER(); LGKM0();                                                    \
        PRIO(1); mma(1, 1, bf1); PRIO(0);                                      \
        BARRIER();                                                             \
        /* P3: Q(fq1,b0), 0 reads, regs only -> NO entry barrier needed:      \
           stage S3 targets slots freed >=2 barriers ago; mma uses regs. */    \
        S3;                                                                    \
        PRIO(1); mma(1, 0, bf0); PRIO(0);                                      \
        W3;                                                                    \
        BARRIER();                                                             \
    } while (0)

    // prologue: tile0 fully (8 loads) + {A(1)h0, B(1)h0, B(1)h1} (6 loads);
    // vmcnt(6) drains tile0, leaves exactly the steady-state in-flight trio.
    // A(1)h1 is staged at tile0's P0 per the rotation.
    stageA(0, 0); stageA(0, 1); stageB(0, 0); stageB(0, 1);
    stageA(1, 0); stageB(1, 0); stageB(1, 1);
    asm volatile("s_waitcnt vmcnt(6)" ::: "memory");
    __builtin_amdgcn_s_barrier();

    #pragma unroll 1
    for (int i = 0; i < 15; ++i) {                 // tiles 0..29
        const int t0 = 2 * i, t1 = 2 * i + 1;
        TILE(0,
             { stageA(t0 + 1, 1); },
             { stageA(t0 + 2, 0); },
             { stageB(t0 + 2, 0); },
             { stageB(t0 + 2, 1); },
             asm volatile("s_waitcnt vmcnt(6)" ::: "memory"));
        TILE(1,
             { stageA(t1 + 1, 1); },
             { stageA(t1 + 2, 0); },
             { stageB(t1 + 2, 0); },
             { stageB(t1 + 2, 1); },
             asm volatile("s_waitcnt vmcnt(6)" ::: "memory"));
    }

    // tile 30 (buf 0): P0 stages A(31)h1 (needed); no t+2 stages; drain to 0
    // so tile 31's pieces (A31h0 @t29P1, B31 @t29P2/P3, A31h1 @t30P0) land.
    TILE(0,
         { stageA(31, 1); },
         (void)0, (void)0, (void)0,
         asm volatile("s_waitcnt vmcnt(0)" ::: "memory"));
    // tile 31 (buf 1): no stages, no waits.
    TILE(1, (void)0, (void)0, (void)0, (void)0, (void)0);

#undef TILE
#undef PRIO
#undef LGKM0
#undef BARRIER
#undef GLDS

    // epilogue: C/D layout col = lane&15, row = (lane>>4)*4 + reg  [m89/m91-verified]
    // f-th M-frag at global 16-row block (2f + wm); j = bh*2+v -> col block j.
    #pragma unroll
    for (int j = 0; j < 4; ++j) {
        const int n  = bcol0 + wn * 64 + j * 16 + r;
        const float sc = ldexpf(1.0f, sexp[n]);   // exact power-of-two scale
        const float bs = bias[n];
        #pragma unroll
        for (int f = 0; f < 8; ++f) {
            const int m = brow0 + (2 * f + wm) * 16 + q * 4;
            float* cp = C + (size_t)m * NT + n;
            #pragma unroll
            for (int t = 0; t < 4; ++t)
                cp[(size_t)t * NT] = acc[f][j][t] * sc + bs;
        }
    }
}

// ---- fallback (no workspace): old verified fused 128x128 kernel ----

__device__ __forceinline__ int swzf(int row, int c) { return row * 8 + ((c + row) & 7); }

__global__ __launch_bounds__(256) void gemm_fb(
    const float* __restrict__ Af32, const int* __restrict__ Wi32,
    const int* __restrict__ sexp, const float* __restrict__ bias,
    float* __restrict__ C)
{
    __shared__ unsigned short As[128 * 64];
    __shared__ unsigned short Bs[128 * 64];

    const int tid  = threadIdx.x;
    const int row0 = blockIdx.y * 128;
    const int col0 = blockIdx.x * 128;
    const int lane = tid & 63;
    const int wave = tid >> 6;
    const int wm = wave >> 1, wn = wave & 1;
    const int q = lane >> 4, r = lane & 15;

    f32x4 acc[4][4] = {};

    for (int k0 = 0; k0 < KT; k0 += 64) {
        #pragma unroll
        for (int ii = 0; ii < 8; ++ii) {
            const int s  = tid + ii * 256;
            const int rw = s >> 4, c4 = s & 15;
            const int ch = c4 >> 1, hf = c4 & 1;
            const int ps = ((ch + rw) & 7) * 8 + hf * 4;
            float4 v = *(const float4*)(Af32 + (size_t)(row0 + rw) * KT + k0 + c4 * 4);
            ushort4v oa;
            oa[0] = f32_bf16(v.x); oa[1] = f32_bf16(v.y);
            oa[2] = f32_bf16(v.z); oa[3] = f32_bf16(v.w);
            *(ushort4v*)(As + rw * 64 + ps) = oa;
            int4 w4 = *(const int4*)(Wi32 + (size_t)(col0 + rw) * KT + k0 + c4 * 4);
            ushort4v ob;
            ob[0] = f32_bf16((float)w4.x); ob[1] = f32_bf16((float)w4.y);
            ob[2] = f32_bf16((float)w4.z); ob[3] = f32_bf16((float)w4.w);
            *(ushort4v*)(Bs + rw * 64 + ps) = ob;
        }
        __syncthreads();
        #pragma unroll
        for (int h = 0; h < 2; ++h) {
            short8 a[4], b[4];
            #pragma unroll
            for (int i = 0; i < 4; ++i)
                a[i] = *(const short8*)(As + swzf(wm * 64 + i * 16 + r, h * 4 + q) * 8);
            #pragma unroll
            for (int j = 0; j < 4; ++j)
                b[j] = *(const short8*)(Bs + swzf(wn * 64 + j * 16 + r, h * 4 + q) * 8);
            #pragma unroll
            for (int i = 0; i < 4; ++i)
                #pragma unroll
                for (int j = 0; j < 4; ++j)
                    acc[i][j] = __builtin_amdgcn_mfma_f32_16x16x32_bf16(a[i], b[j], acc[i][j], 0, 0, 0);
        }
        __syncthreads();
    }

    #pragma unroll
    for (int j = 0; j < 4; ++j) {
        const int n  = col0 + wn * 64 + j * 16 + r;
        const float sc = ldexpf(1.0f, sexp[n]);
        const float bs = bias[n];
        #pragma unroll
        for (int i = 0; i < 4; ++i) {
            const int m = row0 + wm * 64 + i * 16 + q * 4;
            float* cp = C + (size_t)m * NT + n;
            #pragma unroll
            for (int t = 0; t < 4; ++t)
                cp[(size_t)t * NT] = acc[i][j][t] * sc + bs;
        }
    }
}

extern "C" void kernel_launch(void* const* d_in, const int* in_sizes, int n_in,
                              void* d_out, int out_size, void* d_ws, size_t ws_size,
                              hipStream_t stream) {
    const float* x    = (const float*)d_in[0];
    const int*   wq   = (const int*)d_in[1];   // ternary {-1,0,1}, int32 per harness
    const int*   se   = (const int*)d_in[2];   // exponents [-8,0]
    const float* bias = (const float*)d_in[3];
    float* out = (float*)d_out;

    const size_t xb_elems = (size_t)MT * KT;   // 33554432
    const size_t wb_elems = (size_t)NT * KT;   // 4194304

    if (ws_size >= (xb_elems + wb_elems) * sizeof(unsigned short)) {
        unsigned short* xb = (unsigned short*)d_ws;
        unsigned short* wb = xb + xb_elems;
        cvt_kernel<<<(int)((xb_elems + wb_elems) / (256 * 8)), 256, 0, stream>>>(x, wq, xb, wb);
        gemm_8ph<<<dim3(512), THREADS, 0, stream>>>(xb, wb, se, bias, out);  // XCD-chunked 1-D
    } else {
        dim3 fgrid(NT / 128, MT / 128);        // (16, 128)
        gemm_fb<<<fgrid, 256, 0, stream>>>(x, wq, se, bias, out);
    }
}